// Round 4
// baseline (213.399 us; speedup 1.0000x reference)
//
#include <hip/hip_runtime.h>
#include <hip/hip_bf16.h>

typedef float f32x4  __attribute__((ext_vector_type(4)));
typedef float f32x16 __attribute__((ext_vector_type(16)));
typedef short s16x8  __attribute__((ext_vector_type(8)));
typedef unsigned int u32;

#define NB 4
#define NC 128
#define NNPOS 4096
#define KSP 8          // 8 splits, nq=2 -> 2048 waves = 2/SIMD, 512 blocks = 2/CU exact
#define LOG2E 1.44269504088896f

__device__ __forceinline__ short bf16s(float x) {
    __hip_bfloat16 h = __float2bfloat16(x);
    return *reinterpret_cast<short*>(&h);
}
__device__ __forceinline__ int packbf2(float lo, float hi) {
    __hip_bfloat162 t = __float22bfloat162_rn(float2{lo, hi});
    return *reinterpret_cast<int*>(&t);
}
__device__ __forceinline__ float bf2f(unsigned short u) {
    unsigned int v = ((unsigned int)u) << 16;
    return *reinterpret_cast<float*>(&v);
}
__device__ __forceinline__ float exp2fast(float x) {
    return __builtin_amdgcn_exp2f(x);   // native v_exp_f32 (base 2)
}
__device__ __forceinline__ void gload_lds16(const short* g, short* l) {
    __builtin_amdgcn_global_load_lds(
        (const __attribute__((address_space(1))) u32*)g,
        (__attribute__((address_space(3))) u32*)l, 16, 0, 0);
}

// exp2 + pack one 16-score vector into two PV A-frags.
// Consumes sv immediately (score regs die before the next score MFMA
// issues -> peak score liveness 16 regs instead of 32; R13 pressure fix).
// lp add order identical to R12 (absmax-stable).
__device__ __forceinline__ void exppack(const f32x16& sv, s16x8& plo, s16x8& phi,
                                        float& l0, float& l1) {
    union { int i[4]; s16x8 v; } u;
    #pragma unroll
    for (int j = 0; j < 4; ++j) {
        float p0 = exp2fast(sv[2 * j]);
        float p1 = exp2fast(sv[2 * j + 1]);
        if (j & 1) l1 += p0 + p1; else l0 += p0 + p1;
        u.i[j] = packbf2(p0, p1);
    }
    plo = u.v;
    #pragma unroll
    for (int j = 0; j < 4; ++j) {
        float p0 = exp2fast(sv[8 + 2 * j]);
        float p1 = exp2fast(sv[8 + 2 * j + 1]);
        if (j & 1) l1 += p0 + p1; else l0 += p0 + p1;
        u.i[j] = packbf2(p0, p1);
    }
    phi = u.v;
}

// ------------------------------------------------------------------
// Kernel 1: QKV projection via bf16 MFMA 16x16x32 (R13: + zero the
// split-K completion counters; kernel boundary orders this before attn).
// vt layout: linear-lane order so attn can stage it with
// global_load_lds (wave-uniform base + lane*16B, m104):
//   short_idx = ((b*256+kg)*4 + ct)*512 + (slot>>3)*256 + (c&31)*8 + (slot&7)
// slot = swap-bits-2,3 of (key%16).
// ------------------------------------------------------------------
__global__ __launch_bounds__(256) void qkv_kernel(
    const float* __restrict__ x,
    const float* __restrict__ wq, const float* __restrict__ bq,
    const float* __restrict__ wk, const float* __restrict__ bk,
    const float* __restrict__ wv, const float* __restrict__ bv,
    short* __restrict__ qb, short* __restrict__ kb, short* __restrict__ vt,
    int* __restrict__ cnt)
{
    const int n0  = blockIdx.x * 32;
    const int b   = blockIdx.y;
    const int tid = threadIdx.x;
    const int w = tid >> 6, lane = tid & 63, quad = lane >> 4, nn = lane & 15;

    if (blockIdx.x == 0 && tid < 16) cnt[b * 16 + tid] = 0;

    __shared__ __align__(16) short xsT[32 * 136];
    __shared__ __align__(16) short vstage[4096];   // 2 kg x 4 ct x 512

    #pragma unroll
    for (int p = 0; p < 4; ++p) {
        int idx = tid + p * 256;
        int cc = idx >> 3, n4 = (idx & 7) * 4;
        f32x4 xv = *(const f32x4*)&x[((size_t)(b * NC + cc)) * NNPOS + n0 + n4];
        #pragma unroll
        for (int j = 0; j < 4; ++j)
            xsT[(n4 + j) * 136 + cc] = bf16s(xv[j]);
    }

    s16x8 af[3][4];
    bool  live[3];
    f32x4 biasv[3];
    #pragma unroll
    for (int t = 0; t < 3; ++t) {
        int rid = 3 * w + t;
        int R   = rid * 16;
        const float* wsrc = nullptr; const float* bsrc = nullptr; int row0 = 0;
        float scale = 1.0f;
        if (rid < 8)        { wsrc = wv; bsrc = bv; row0 = R; }
        else if (rid == 8)  { wsrc = wq; bsrc = bq; row0 = 0; scale = LOG2E; }
        else if (rid == 10) { wsrc = wk; bsrc = bk; row0 = 0; }
        live[t] = (wsrc != nullptr);
        #pragma unroll
        for (int r = 0; r < 4; ++r)
            biasv[t][r] = live[t] ? scale * bsrc[row0 + quad * 4 + r] : 0.0f;
        if (live[t]) {
            #pragma unroll
            for (int ks = 0; ks < 4; ++ks) {
                const float* src = wsrc + (size_t)(row0 + nn) * NC + ks * 32 + quad * 8;
                f32x4 wa = *(const f32x4*)src;
                f32x4 wb = *(const f32x4*)(src + 4);
                s16x8 f;
                #pragma unroll
                for (int j = 0; j < 4; ++j) {
                    f[j]     = bf16s(scale * wa[j]);
                    f[j + 4] = bf16s(scale * wb[j]);
                }
                af[t][ks] = f;
            }
        }
    }
    __syncthreads();

    f32x4 acc[3][2];
    #pragma unroll
    for (int t = 0; t < 3; ++t)
        #pragma unroll
        for (int nt = 0; nt < 2; ++nt)
            acc[t][nt] = biasv[t];

    #pragma unroll
    for (int nt = 0; nt < 2; ++nt) {
        s16x8 bf[4];
        #pragma unroll
        for (int ks = 0; ks < 4; ++ks)
            bf[ks] = *(const s16x8*)&xsT[(nt * 16 + nn) * 136 + ks * 32 + quad * 8];
        #pragma unroll
        for (int t = 0; t < 3; ++t)
            if (live[t])
                #pragma unroll
                for (int ks = 0; ks < 4; ++ks)
                    acc[t][nt] = __builtin_amdgcn_mfma_f32_16x16x32_bf16(af[t][ks], bf[ks], acc[t][nt], 0, 0, 0);
    }

    // V-slot key permutation: swap bits 2<->3 of (key%16)
    const int slot = (nn & 3) | ((nn & 4) << 1) | ((nn & 8) >> 1);

    #pragma unroll
    for (int t = 0; t < 3; ++t) {
        if (!live[t]) continue;
        const int rid = 3 * w + t;
        #pragma unroll
        for (int nt = 0; nt < 2; ++nt) {
            if (rid < 8) {
                #pragma unroll
                for (int r = 0; r < 4; ++r) {
                    int row = rid * 16 + quad * 4 + r;
                    vstage[(((nt << 2) | (row >> 5)) << 9) +
                           ((slot >> 3) << 8) + ((row & 31) << 3) + (slot & 7)]
                        = bf16s(acc[t][nt][r]);
                }
            } else {
                short4 pk;
                pk.x = bf16s(acc[t][nt][0]);
                pk.y = bf16s(acc[t][nt][1]);
                pk.z = bf16s(acc[t][nt][2]);
                pk.w = bf16s(acc[t][nt][3]);
                int n = n0 + nt * 16 + nn;
                short* dst = (rid == 8 ? qb : kb) +
                             ((size_t)(b * NNPOS) + n) * 16 + quad * 4;
                *reinterpret_cast<short4*>(dst) = pk;
            }
        }
    }
    __syncthreads();

    // coalesced copy-out: 8 KB tile, 256 threads x 2 x 16B
    {
        short* vdst = vt + ((size_t)(b * 256) + (n0 >> 4)) * 2048;
        #pragma unroll
        for (int p = 0; p < 2; ++p) {
            int off = (tid + p * 256) * 8;
            *(s16x8*)&vdst[off] = *(const s16x8*)&vstage[off];
        }
    }
}

// ------------------------------------------------------------------
// Kernel 2: flash attention (nq=2, shared LDS V, double-buffered) +
// R13 split-K TAIL COMBINE: last-arriving split-block per (b, 256-q
// tile) re-reads all 8 partials (L2-hot) and writes the final output
// (old combine_kernel body, 4x 64-n tiles through an LDS transpose).
// Device-scope fence pattern per G16: stores -> __threadfence ->
// atomicAdd; last block: atomic -> __threadfence -> reads.
// R13 pressure fix: s0 consumed by exppack before s1 is computed
// (peak score liveness 16 regs, worst-point total ~244 < 256).
// ------------------------------------------------------------------
__global__ __launch_bounds__(256, 2) void attn_kernel(
    const short* __restrict__ qb, const short* __restrict__ kb,
    const short* __restrict__ vt,
    unsigned short* __restrict__ Ow, float* __restrict__ lw,
    const float* __restrict__ xg, const float* __restrict__ gamma,
    float* __restrict__ out, int* __restrict__ cnt)
{
    const int s   = blockIdx.x;    // key split 0..7
    const int qy  = blockIdx.y;    // 256-q tile 0..15
    const int b   = blockIdx.z;
    const int tid = threadIdx.x;
    const int w = tid >> 6, lane = tid & 63, h = lane >> 5, c31 = lane & 31;

    const int q0 = (qy * 4 + w) * 64;   // wave's 64-query super-tile

    // smem carve: attn phase uses vlds[2][8192] shorts (32KB);
    // combine phase reuses it as ot[128*65] + lsum[64] floats (33.5KB).
    __shared__ __align__(16) char smem[33536];
    short (*vlds)[8192] = (short (*)[8192])smem;
    __shared__ int isLast;

    s16x8 bqA = *(const s16x8*)(qb + ((size_t)(b * NNPOS) + q0      + c31) * 16 + h * 8);
    s16x8 bqB = *(const s16x8*)(qb + ((size_t)(b * NNPOS) + q0 + 32 + c31) * 16 + h * 8);

    f32x16 acc[2][4];
    #pragma unroll
    for (int t = 0; t < 2; ++t)
        #pragma unroll
        for (int ct = 0; ct < 4; ++ct)
            #pragma unroll
            for (int r = 0; r < 16; ++r) acc[t][ct][r] = 0.0f;
    float lpA0 = 0.f, lpA1 = 0.f, lpB0 = 0.f, lpB1 = 0.f;

    const short* kbp = kb + (size_t)(b * NNPOS) * 16;
    const int mbase  = s * (NNPOS / KSP);               // 512 keys/split
    const short* vtile = vt + (size_t)b * (NC * NNPOS) + ((size_t)(mbase >> 4) << 11);

    f32x16 z;
    #pragma unroll
    for (int r = 0; r < 16; ++r) z[r] = 0.0f;

    // prologue: stage iter 0 into buf 0; prefetch K for iter 0
    #pragma unroll
    for (int j = 0; j < 4; ++j)
        gload_lds16(vtile + (tid << 3) + (j << 11),
                    &vlds[0][0] + (tid << 3) + (j << 11));
    int m0 = mbase;
    s16x8 ak0 = *(const s16x8*)(kbp + (size_t)(m0      + c31) * 16 + h * 8);
    s16x8 ak1 = *(const s16x8*)(kbp + (size_t)(m0 + 32 + c31) * 16 + h * 8);
    __syncthreads();

    int buf = 0;
    #pragma unroll 1
    for (int it = 0; it < NNPOS / KSP / 64; ++it) {      // 8 iters
        // issue next-tile V staging into the other buffer
        if (it + 1 < NNPOS / KSP / 64) {
            const short* src = vtile + (((size_t)(it + 1)) << 13);
            short* dst = &vlds[buf ^ 1][0];
            #pragma unroll
            for (int j = 0; j < 4; ++j)
                gload_lds16(src + (tid << 3) + (j << 11),
                            dst + (tid << 3) + (j << 11));
        }

        // scores -> exp/pack, sequential per score vector (pressure fix)
        s16x8 paA[4], paB[4];
        {
            f32x16 sc = __builtin_amdgcn_mfma_f32_32x32x16_bf16(ak0, bqA, z, 0, 0, 0);
            exppack(sc, paA[0], paA[1], lpA0, lpA1);
            sc = __builtin_amdgcn_mfma_f32_32x32x16_bf16(ak1, bqA, z, 0, 0, 0);
            exppack(sc, paA[2], paA[3], lpA0, lpA1);
            sc = __builtin_amdgcn_mfma_f32_32x32x16_bf16(ak0, bqB, z, 0, 0, 0);
            exppack(sc, paB[0], paB[1], lpB0, lpB1);
            sc = __builtin_amdgcn_mfma_f32_32x32x16_bf16(ak1, bqB, z, 0, 0, 0);
            exppack(sc, paB[2], paB[3], lpB0, lpB1);
        }

        // prefetch next iter's K (ak0/ak1 dead after the score MFMAs)
        if (it + 1 < NNPOS / KSP / 64) {
            m0 += 64;
            ak0 = *(const s16x8*)(kbp + (size_t)(m0      + c31) * 16 + h * 8);
            ak1 = *(const s16x8*)(kbp + (size_t)(m0 + 32 + c31) * 16 + h * 8);
        }

        // PV: one ds_read_b128 per (p,ct) feeds BOTH q-tiles' MFMAs
        const short* vb = &vlds[buf][0];
        #pragma unroll
        for (int p = 0; p < 4; ++p)
            #pragma unroll
            for (int ct = 0; ct < 4; ++ct) {
                s16x8 vf = *(const s16x8*)&vb[((p * 4 + ct) << 9) + (lane << 3)];
                acc[0][ct] = __builtin_amdgcn_mfma_f32_32x32x16_bf16(
                    paA[p], vf, acc[0][ct], 0, 0, 0);
                acc[1][ct] = __builtin_amdgcn_mfma_f32_32x32x16_bf16(
                    paB[p], vf, acc[1][ct], 0, 0, 0);
            }

        __syncthreads();   // staging of it+1 complete; reads of buf done
        buf ^= 1;
    }

    float lpA = lpA0 + lpA1;
    float lpB = lpB0 + lpB1;
    lpA += __shfl_xor(lpA, 32, 64);
    lpB += __shfl_xor(lpB, 32, 64);
    if (lane < 32) {
        lw[((size_t)(b * KSP + s)) * NNPOS + q0      + c31] = lpA;
        lw[((size_t)(b * KSP + s)) * NNPOS + q0 + 32 + c31] = lpB;
    }

    // O partial: [b][s][n][c] bf16 (both q-tiles)
    #pragma unroll
    for (int ct = 0; ct < 4; ++ct)
        #pragma unroll
        for (int r = 0; r < 16; ++r) {
            int q = q0 + (r & 3) + 8 * (r >> 2) + 4 * h;
            Ow[(((size_t)(b * KSP + s)) * NNPOS + q) * NC + ct * 32 + c31] =
                (unsigned short)bf16s(acc[0][ct][r]);
            Ow[(((size_t)(b * KSP + s)) * NNPOS + q + 32) * NC + ct * 32 + c31] =
                (unsigned short)bf16s(acc[1][ct][r]);
        }

    // ---- split-K completion: last block of the 8 combines ----
    __threadfence();                       // publish Ow/lw (device scope)
    if (tid == 0) {
        int old = atomicAdd(&cnt[b * 16 + qy], 1);
        isLast = (old == KSP - 1);
    }
    __syncthreads();                       // broadcast + vlds reads done
    if (!isLast) return;
    __threadfence();                       // acquire side

    // combine 4x 64-n tiles (old combine_kernel body, same math/order)
    float* ot   = (float*)smem;            // [128*65]
    float* lsum = ot + 128 * 65;           // [64]
    const float g = gamma[0];

    #pragma unroll 1
    for (int tI = 0; tI < 4; ++tI) {
        const int n0c = qy * 256 + tI * 64;

        if (tid < 64) {
            float sl = 0.f;
            #pragma unroll
            for (int sI = 0; sI < KSP; ++sI)
                sl += lw[((size_t)(b * KSP + sI)) * NNPOS + n0c + tid];
            lsum[tid] = 1.0f / sl;
        }
        __syncthreads();

        #pragma unroll
        for (int p = 0; p < 4; ++p) {
            int e = tid + p * 256;          // over 16 c-octs x 64 n
            int co = e & 15, n = e >> 4;
            float a[8] = {0.f, 0.f, 0.f, 0.f, 0.f, 0.f, 0.f, 0.f};
            #pragma unroll
            for (int sI = 0; sI < KSP; ++sI) {
                const unsigned short* src = Ow +
                    (((size_t)(b * KSP + sI)) * NNPOS + n0c + n) * NC + co * 8;
                union { s16x8 v; unsigned short us[8]; } u;
                u.v = *(const s16x8*)src;
                #pragma unroll
                for (int j = 0; j < 8; ++j) a[j] += bf2f(u.us[j]);
            }
            float inv = lsum[n];
            #pragma unroll
            for (int j = 0; j < 8; ++j)
                ot[(co * 8 + j) * 65 + n] = a[j] * inv;
        }
        __syncthreads();

        #pragma unroll
        for (int p = 0; p < 8; ++p) {
            int e = tid + p * 256;          // over 128 c x 16 n-quads
            int nq = e & 15, c = e >> 4;
            size_t a = ((size_t)(b * NC + c)) * NNPOS + n0c + nq * 4;
            float4 xv = *(const float4*)&xg[a];
            float4 o;
            o.x = g * ot[c * 65 + nq * 4]     + xv.x;
            o.y = g * ot[c * 65 + nq * 4 + 1] + xv.y;
            o.z = g * ot[c * 65 + nq * 4 + 2] + xv.z;
            o.w = g * ot[c * 65 + nq * 4 + 3] + xv.w;
            *(float4*)&out[a] = o;
        }
        __syncthreads();                    // ot reused next tI
    }
}

// ------------------------------------------------------------------
extern "C" void kernel_launch(void* const* d_in, const int* in_sizes, int n_in,
                              void* d_out, int out_size, void* d_ws, size_t ws_size,
                              hipStream_t stream) {
    const float* x     = (const float*)d_in[0];
    const float* wq    = (const float*)d_in[1];
    const float* bq    = (const float*)d_in[2];
    const float* wk    = (const float*)d_in[3];
    const float* bk    = (const float*)d_in[4];
    const float* wv    = (const float*)d_in[5];
    const float* bv    = (const float*)d_in[6];
    const float* gamma = (const float*)d_in[7];
    float* out = (float*)d_out;

    // ws: qb 512KB | kb 512KB | vt 4MB | Ow 33.5MB | lw 512KB | cnt 256B
    short* qb = (short*)d_ws;
    short* kb = qb + (size_t)NB * NNPOS * 16;
    short* vt = kb + (size_t)NB * NNPOS * 16;
    unsigned short* Ow = (unsigned short*)(vt + (size_t)NB * NC * NNPOS);
    float* lw = (float*)(Ow + (size_t)NB * KSP * NNPOS * NC);
    int* cnt = (int*)(lw + (size_t)NB * KSP * NNPOS);

    qkv_kernel<<<dim3(128, NB), 256, 0, stream>>>(x, wq, bq, wk, bk, wv, bv, qb, kb, vt, cnt);
    attn_kernel<<<dim3(KSP, 16, NB), 256, 0, stream>>>(qb, kb, vt, Ow, lw, x, gamma, out, cnt);
}

// Round 5
// 114.603 us; speedup vs baseline: 1.8621x; 1.8621x over previous
//
#include <hip/hip_runtime.h>
#include <hip/hip_bf16.h>

typedef float f32x4  __attribute__((ext_vector_type(4)));
typedef float f32x16 __attribute__((ext_vector_type(16)));
typedef short s16x8  __attribute__((ext_vector_type(8)));
typedef unsigned int u32;

#define NB 4
#define NC 128
#define NNPOS 4096
#define KSP 8          // 8 splits, nq=2 -> 2048 waves = 2/SIMD, 512 blocks = 2/CU exact
#define LOG2E 1.44269504088896f

__device__ __forceinline__ short bf16s(float x) {
    __hip_bfloat16 h = __float2bfloat16(x);
    return *reinterpret_cast<short*>(&h);
}
__device__ __forceinline__ int packbf2(float lo, float hi) {
    __hip_bfloat162 t = __float22bfloat162_rn(float2{lo, hi});
    return *reinterpret_cast<int*>(&t);
}
__device__ __forceinline__ float bf2f(unsigned short u) {
    unsigned int v = ((unsigned int)u) << 16;
    return *reinterpret_cast<float*>(&v);
}
__device__ __forceinline__ float exp2fast(float x) {
    return __builtin_amdgcn_exp2f(x);   // native v_exp_f32 (base 2)
}
__device__ __forceinline__ void gload_lds16(const short* g, short* l) {
    __builtin_amdgcn_global_load_lds(
        (const __attribute__((address_space(1))) u32*)g,
        (__attribute__((address_space(3))) u32*)l, 16, 0, 0);
}

// exp2 + pack one 16-score vector into two PV A-frags.
// Consumes sv immediately (score regs die before the next score MFMA
// issues -> peak score liveness 16 regs instead of 32).
// lp add order identical to R12 (absmax-stable).
__device__ __forceinline__ void exppack(const f32x16& sv, s16x8& plo, s16x8& phi,
                                        float& l0, float& l1) {
    union { int i[4]; s16x8 v; } u;
    #pragma unroll
    for (int j = 0; j < 4; ++j) {
        float p0 = exp2fast(sv[2 * j]);
        float p1 = exp2fast(sv[2 * j + 1]);
        if (j & 1) l1 += p0 + p1; else l0 += p0 + p1;
        u.i[j] = packbf2(p0, p1);
    }
    plo = u.v;
    #pragma unroll
    for (int j = 0; j < 4; ++j) {
        float p0 = exp2fast(sv[8 + 2 * j]);
        float p1 = exp2fast(sv[8 + 2 * j + 1]);
        if (j & 1) l1 += p0 + p1; else l0 += p0 + p1;
        u.i[j] = packbf2(p0, p1);
    }
    phi = u.v;
}

// ------------------------------------------------------------------
// Kernel 1: QKV projection via bf16 MFMA 16x16x32.
// vt layout: linear-lane order so attn can stage it with
// global_load_lds (wave-uniform base + lane*16B, m104):
//   short_idx = ((b*256+kg)*4 + ct)*512 + (slot>>3)*256 + (c&31)*8 + (slot&7)
// slot = swap-bits-2,3 of (key%16).
// ------------------------------------------------------------------
__global__ __launch_bounds__(256) void qkv_kernel(
    const float* __restrict__ x,
    const float* __restrict__ wq, const float* __restrict__ bq,
    const float* __restrict__ wk, const float* __restrict__ bk,
    const float* __restrict__ wv, const float* __restrict__ bv,
    short* __restrict__ qb, short* __restrict__ kb, short* __restrict__ vt)
{
    const int n0  = blockIdx.x * 32;
    const int b   = blockIdx.y;
    const int tid = threadIdx.x;
    const int w = tid >> 6, lane = tid & 63, quad = lane >> 4, nn = lane & 15;

    __shared__ __align__(16) short xsT[32 * 136];
    __shared__ __align__(16) short vstage[4096];   // 2 kg x 4 ct x 512

    #pragma unroll
    for (int p = 0; p < 4; ++p) {
        int idx = tid + p * 256;
        int cc = idx >> 3, n4 = (idx & 7) * 4;
        f32x4 xv = *(const f32x4*)&x[((size_t)(b * NC + cc)) * NNPOS + n0 + n4];
        #pragma unroll
        for (int j = 0; j < 4; ++j)
            xsT[(n4 + j) * 136 + cc] = bf16s(xv[j]);
    }

    s16x8 af[3][4];
    bool  live[3];
    f32x4 biasv[3];
    #pragma unroll
    for (int t = 0; t < 3; ++t) {
        int rid = 3 * w + t;
        int R   = rid * 16;
        const float* wsrc = nullptr; const float* bsrc = nullptr; int row0 = 0;
        float scale = 1.0f;
        if (rid < 8)        { wsrc = wv; bsrc = bv; row0 = R; }
        else if (rid == 8)  { wsrc = wq; bsrc = bq; row0 = 0; scale = LOG2E; }
        else if (rid == 10) { wsrc = wk; bsrc = bk; row0 = 0; }
        live[t] = (wsrc != nullptr);
        #pragma unroll
        for (int r = 0; r < 4; ++r)
            biasv[t][r] = live[t] ? scale * bsrc[row0 + quad * 4 + r] : 0.0f;
        if (live[t]) {
            #pragma unroll
            for (int ks = 0; ks < 4; ++ks) {
                const float* src = wsrc + (size_t)(row0 + nn) * NC + ks * 32 + quad * 8;
                f32x4 wa = *(const f32x4*)src;
                f32x4 wb = *(const f32x4*)(src + 4);
                s16x8 f;
                #pragma unroll
                for (int j = 0; j < 4; ++j) {
                    f[j]     = bf16s(scale * wa[j]);
                    f[j + 4] = bf16s(scale * wb[j]);
                }
                af[t][ks] = f;
            }
        }
    }
    __syncthreads();

    f32x4 acc[3][2];
    #pragma unroll
    for (int t = 0; t < 3; ++t)
        #pragma unroll
        for (int nt = 0; nt < 2; ++nt)
            acc[t][nt] = biasv[t];

    #pragma unroll
    for (int nt = 0; nt < 2; ++nt) {
        s16x8 bf[4];
        #pragma unroll
        for (int ks = 0; ks < 4; ++ks)
            bf[ks] = *(const s16x8*)&xsT[(nt * 16 + nn) * 136 + ks * 32 + quad * 8];
        #pragma unroll
        for (int t = 0; t < 3; ++t)
            if (live[t])
                #pragma unroll
                for (int ks = 0; ks < 4; ++ks)
                    acc[t][nt] = __builtin_amdgcn_mfma_f32_16x16x32_bf16(af[t][ks], bf[ks], acc[t][nt], 0, 0, 0);
    }

    // V-slot key permutation: swap bits 2<->3 of (key%16)
    const int slot = (nn & 3) | ((nn & 4) << 1) | ((nn & 8) >> 1);

    #pragma unroll
    for (int t = 0; t < 3; ++t) {
        if (!live[t]) continue;
        const int rid = 3 * w + t;
        #pragma unroll
        for (int nt = 0; nt < 2; ++nt) {
            if (rid < 8) {
                #pragma unroll
                for (int r = 0; r < 4; ++r) {
                    int row = rid * 16 + quad * 4 + r;
                    vstage[(((nt << 2) | (row >> 5)) << 9) +
                           ((slot >> 3) << 8) + ((row & 31) << 3) + (slot & 7)]
                        = bf16s(acc[t][nt][r]);
                }
            } else {
                short4 pk;
                pk.x = bf16s(acc[t][nt][0]);
                pk.y = bf16s(acc[t][nt][1]);
                pk.z = bf16s(acc[t][nt][2]);
                pk.w = bf16s(acc[t][nt][3]);
                int n = n0 + nt * 16 + nn;
                short* dst = (rid == 8 ? qb : kb) +
                             ((size_t)(b * NNPOS) + n) * 16 + quad * 4;
                *reinterpret_cast<short4*>(dst) = pk;
            }
        }
    }
    __syncthreads();

    // coalesced copy-out: 8 KB tile, 256 threads x 2 x 16B
    {
        short* vdst = vt + ((size_t)(b * 256) + (n0 >> 4)) * 2048;
        #pragma unroll
        for (int p = 0; p < 2; ++p) {
            int off = (tid + p * 256) * 8;
            *(s16x8*)&vdst[off] = *(const s16x8*)&vstage[off];
        }
    }
}

// ------------------------------------------------------------------
// Kernel 2: flash attention, S^T formulation, mfma 32x32x16.
// R14: R12 structure restored (NO device fences / tail combine -- the
// R13 __threadfence per-block L2-writeback storm cost +100us on this
// multi-XCD chip; kernel boundary provides that coherence for free).
// Kept from R13: exppack (score regs consumed immediately, peak score
// liveness 16 not 32).
// nq=2: each wave owns TWO 32-query tiles sharing every LDS V fragment
// (one ds_read_b128 feeds 2 PV MFMAs). KSP=8, grid (8,16,4)=512 blocks
// = 2/CU, 2048 waves = 2/SIMD. V staged double-buffered in LDS via
// global_load_lds (32KB/block); one barrier per iter; K per-wave in
// regs with 1-iter prefetch.
// ------------------------------------------------------------------
__global__ __launch_bounds__(256, 2) void attn_kernel(
    const short* __restrict__ qb, const short* __restrict__ kb,
    const short* __restrict__ vt,
    unsigned short* __restrict__ Ow, float* __restrict__ lw)
{
    const int s   = blockIdx.x;    // key split 0..7
    const int b   = blockIdx.z;
    const int tid = threadIdx.x;
    const int w = tid >> 6, lane = tid & 63, h = lane >> 5, c31 = lane & 31;

    const int q0 = (blockIdx.y * 4 + w) * 64;   // wave's 64-query super-tile

    __shared__ __align__(16) short vlds[2][8192];   // 2 x 16KB (64 keys x 128c)

    s16x8 bqA = *(const s16x8*)(qb + ((size_t)(b * NNPOS) + q0      + c31) * 16 + h * 8);
    s16x8 bqB = *(const s16x8*)(qb + ((size_t)(b * NNPOS) + q0 + 32 + c31) * 16 + h * 8);

    f32x16 acc[2][4];
    #pragma unroll
    for (int t = 0; t < 2; ++t)
        #pragma unroll
        for (int ct = 0; ct < 4; ++ct)
            #pragma unroll
            for (int r = 0; r < 16; ++r) acc[t][ct][r] = 0.0f;
    float lpA0 = 0.f, lpA1 = 0.f, lpB0 = 0.f, lpB1 = 0.f;

    const short* kbp = kb + (size_t)(b * NNPOS) * 16;
    const int mbase  = s * (NNPOS / KSP);               // 512 keys/split
    const short* vtile = vt + (size_t)b * (NC * NNPOS) + ((size_t)(mbase >> 4) << 11);

    f32x16 z;
    #pragma unroll
    for (int r = 0; r < 16; ++r) z[r] = 0.0f;

    // prologue: stage iter 0 into buf 0; prefetch K for iter 0
    #pragma unroll
    for (int j = 0; j < 4; ++j)
        gload_lds16(vtile + (tid << 3) + (j << 11),
                    &vlds[0][0] + (tid << 3) + (j << 11));
    int m0 = mbase;
    s16x8 ak0 = *(const s16x8*)(kbp + (size_t)(m0      + c31) * 16 + h * 8);
    s16x8 ak1 = *(const s16x8*)(kbp + (size_t)(m0 + 32 + c31) * 16 + h * 8);
    __syncthreads();

    int buf = 0;
    #pragma unroll 1
    for (int it = 0; it < NNPOS / KSP / 64; ++it) {      // 8 iters
        // issue next-tile V staging into the other buffer
        if (it + 1 < NNPOS / KSP / 64) {
            const short* src = vtile + (((size_t)(it + 1)) << 13);
            short* dst = &vlds[buf ^ 1][0];
            #pragma unroll
            for (int j = 0; j < 4; ++j)
                gload_lds16(src + (tid << 3) + (j << 11),
                            dst + (tid << 3) + (j << 11));
        }

        // scores -> exp/pack, sequential per score vector (pressure fix)
        s16x8 paA[4], paB[4];
        {
            f32x16 sc = __builtin_amdgcn_mfma_f32_32x32x16_bf16(ak0, bqA, z, 0, 0, 0);
            exppack(sc, paA[0], paA[1], lpA0, lpA1);
            sc = __builtin_amdgcn_mfma_f32_32x32x16_bf16(ak1, bqA, z, 0, 0, 0);
            exppack(sc, paA[2], paA[3], lpA0, lpA1);
            sc = __builtin_amdgcn_mfma_f32_32x32x16_bf16(ak0, bqB, z, 0, 0, 0);
            exppack(sc, paB[0], paB[1], lpB0, lpB1);
            sc = __builtin_amdgcn_mfma_f32_32x32x16_bf16(ak1, bqB, z, 0, 0, 0);
            exppack(sc, paB[2], paB[3], lpB0, lpB1);
        }

        // prefetch next iter's K (ak0/ak1 dead after the score MFMAs)
        if (it + 1 < NNPOS / KSP / 64) {
            m0 += 64;
            ak0 = *(const s16x8*)(kbp + (size_t)(m0      + c31) * 16 + h * 8);
            ak1 = *(const s16x8*)(kbp + (size_t)(m0 + 32 + c31) * 16 + h * 8);
        }

        // PV: one ds_read_b128 per (p,ct) feeds BOTH q-tiles' MFMAs
        const short* vb = &vlds[buf][0];
        #pragma unroll
        for (int p = 0; p < 4; ++p)
            #pragma unroll
            for (int ct = 0; ct < 4; ++ct) {
                s16x8 vf = *(const s16x8*)&vb[((p * 4 + ct) << 9) + (lane << 3)];
                acc[0][ct] = __builtin_amdgcn_mfma_f32_32x32x16_bf16(
                    paA[p], vf, acc[0][ct], 0, 0, 0);
                acc[1][ct] = __builtin_amdgcn_mfma_f32_32x32x16_bf16(
                    paB[p], vf, acc[1][ct], 0, 0, 0);
            }

        __syncthreads();   // staging of it+1 complete; reads of buf done
        buf ^= 1;
    }

    float lpA = lpA0 + lpA1;
    float lpB = lpB0 + lpB1;
    lpA += __shfl_xor(lpA, 32, 64);
    lpB += __shfl_xor(lpB, 32, 64);
    if (lane < 32) {
        lw[((size_t)(b * KSP + s)) * NNPOS + q0      + c31] = lpA;
        lw[((size_t)(b * KSP + s)) * NNPOS + q0 + 32 + c31] = lpB;
    }

    // O partial: [b][s][n][c] bf16 (both q-tiles)
    #pragma unroll
    for (int ct = 0; ct < 4; ++ct)
        #pragma unroll
        for (int r = 0; r < 16; ++r) {
            int q = q0 + (r & 3) + 8 * (r >> 2) + 4 * h;
            Ow[(((size_t)(b * KSP + s)) * NNPOS + q) * NC + ct * 32 + c31] =
                (unsigned short)bf16s(acc[0][ct][r]);
            Ow[(((size_t)(b * KSP + s)) * NNPOS + q + 32) * NC + ct * 32 + c31] =
                (unsigned short)bf16s(acc[1][ct][r]);
        }
}

// ------------------------------------------------------------------
// Kernel 3: combine split-K partials + epilogue.
// out[b][c][n] = gamma * (sum_s O[b][s][n][c]) / (sum_s l[b][s][n]) + x
// ------------------------------------------------------------------
__global__ __launch_bounds__(256) void combine_kernel(
    const unsigned short* __restrict__ Ow, const float* __restrict__ lw,
    const float* __restrict__ x, const float* __restrict__ gamma,
    float* __restrict__ out)
{
    const int n0  = blockIdx.x * 64;
    const int b   = blockIdx.y;
    const int tid = threadIdx.x;

    __shared__ float ot[128 * 65 + 64];
    float* lsum = ot + 128 * 65;

    if (tid < 64) {
        float sl = 0.f;
        #pragma unroll
        for (int sI = 0; sI < KSP; ++sI)
            sl += lw[((size_t)(b * KSP + sI)) * NNPOS + n0 + tid];
        lsum[tid] = 1.0f / sl;
    }
    __syncthreads();

    #pragma unroll
    for (int p = 0; p < 4; ++p) {
        int e = tid + p * 256;          // over 16 c-octs x 64 n
        int co = e & 15, n = e >> 4;
        float a[8] = {0.f, 0.f, 0.f, 0.f, 0.f, 0.f, 0.f, 0.f};
        #pragma unroll
        for (int sI = 0; sI < KSP; ++sI) {
            const unsigned short* src = Ow +
                (((size_t)(b * KSP + sI)) * NNPOS + n0 + n) * NC + co * 8;
            union { s16x8 v; unsigned short us[8]; } u;
            u.v = *(const s16x8*)src;
            #pragma unroll
            for (int j = 0; j < 8; ++j) a[j] += bf2f(u.us[j]);
        }
        float inv = lsum[n];
        #pragma unroll
        for (int j = 0; j < 8; ++j)
            ot[(co * 8 + j) * 65 + n] = a[j] * inv;
    }
    __syncthreads();

    const float g = gamma[0];
    #pragma unroll
    for (int p = 0; p < 8; ++p) {
        int e = tid + p * 256;          // over 128 c x 16 n-quads
        int nq = e & 15, c = e >> 4;
        size_t a = ((size_t)(b * NC + c)) * NNPOS + n0 + nq * 4;
        float4 xv = *(const float4*)&x[a];
        float4 o;
        o.x = g * ot[c * 65 + nq * 4]     + xv.x;
        o.y = g * ot[c * 65 + nq * 4 + 1] + xv.y;
        o.z = g * ot[c * 65 + nq * 4 + 2] + xv.z;
        o.w = g * ot[c * 65 + nq * 4 + 3] + xv.w;
        *(float4*)&out[a] = o;
    }
}

// ------------------------------------------------------------------
extern "C" void kernel_launch(void* const* d_in, const int* in_sizes, int n_in,
                              void* d_out, int out_size, void* d_ws, size_t ws_size,
                              hipStream_t stream) {
    const float* x     = (const float*)d_in[0];
    const float* wq    = (const float*)d_in[1];
    const float* bq    = (const float*)d_in[2];
    const float* wk    = (const float*)d_in[3];
    const float* bk    = (const float*)d_in[4];
    const float* wv    = (const float*)d_in[5];
    const float* bv    = (const float*)d_in[6];
    const float* gamma = (const float*)d_in[7];
    float* out = (float*)d_out;

    // ws: qb 512KB | kb 512KB | vt 4MB | Ow 33.5MB | lw 512KB
    short* qb = (short*)d_ws;
    short* kb = qb + (size_t)NB * NNPOS * 16;
    short* vt = kb + (size_t)NB * NNPOS * 16;
    unsigned short* Ow = (unsigned short*)(vt + (size_t)NB * NC * NNPOS);
    float* lw = (float*)(Ow + (size_t)NB * KSP * NNPOS * NC);

    qkv_kernel<<<dim3(128, NB), 256, 0, stream>>>(x, wq, bq, wk, bk, wv, bv, qb, kb, vt);
    attn_kernel<<<dim3(KSP, 16, NB), 256, 0, stream>>>(qb, kb, vt, Ow, lw);
    combine_kernel<<<dim3(NNPOS / 64, NB), 256, 0, stream>>>(Ow, lw, x, gamma, out);
}

// Round 6
// 111.094 us; speedup vs baseline: 1.9209x; 1.0316x over previous
//
#include <hip/hip_runtime.h>
#include <hip/hip_bf16.h>

typedef float f32x4  __attribute__((ext_vector_type(4)));
typedef float f32x16 __attribute__((ext_vector_type(16)));
typedef short s16x8  __attribute__((ext_vector_type(8)));
typedef unsigned int u32;

#define NB 4
#define NC 128
#define NNPOS 4096
#define LOG2E 1.44269504088896f

__device__ __forceinline__ short bf16s(float x) {
    __hip_bfloat16 h = __float2bfloat16(x);
    return *reinterpret_cast<short*>(&h);
}
__device__ __forceinline__ int packbf2(float lo, float hi) {
    __hip_bfloat162 t = __float22bfloat162_rn(float2{lo, hi});
    return *reinterpret_cast<int*>(&t);
}
__device__ __forceinline__ float exp2fast(float x) {
    return __builtin_amdgcn_exp2f(x);   // native v_exp_f32 (base 2)
}

// exp2 + pack one 16-score vector into two PV A-frags.
// Consumes sv immediately (score regs die before the next score MFMA
// issues -> peak score liveness 16 regs). lp add order as R12/R14.
__device__ __forceinline__ void exppack(const f32x16& sv, s16x8& plo, s16x8& phi,
                                        float& l0, float& l1) {
    union { int i[4]; s16x8 v; } u;
    #pragma unroll
    for (int j = 0; j < 4; ++j) {
        float p0 = exp2fast(sv[2 * j]);
        float p1 = exp2fast(sv[2 * j + 1]);
        if (j & 1) l1 += p0 + p1; else l0 += p0 + p1;
        u.i[j] = packbf2(p0, p1);
    }
    plo = u.v;
    #pragma unroll
    for (int j = 0; j < 4; ++j) {
        float p0 = exp2fast(sv[8 + 2 * j]);
        float p1 = exp2fast(sv[8 + 2 * j + 1]);
        if (j & 1) l1 += p0 + p1; else l0 += p0 + p1;
        u.i[j] = packbf2(p0, p1);
    }
    phi = u.v;
}

// ------------------------------------------------------------------
// Kernel 1: QKV projection via bf16 MFMA 16x16x32 (unchanged from R14).
// vt layout: lane-linear order:
//   short_idx = ((b*256+kg)*4 + ct)*512 + (slot>>3)*256 + (c&31)*8 + (slot&7)
// slot = swap-bits-2,3 of (key%16). Attn lane l reads its PV B-frag at
// exactly l*8 shorts within each (kg,ct) 1KB slab -> dense coalescing.
// ------------------------------------------------------------------
__global__ __launch_bounds__(256) void qkv_kernel(
    const float* __restrict__ x,
    const float* __restrict__ wq, const float* __restrict__ bq,
    const float* __restrict__ wk, const float* __restrict__ bk,
    const float* __restrict__ wv, const float* __restrict__ bv,
    short* __restrict__ qb, short* __restrict__ kb, short* __restrict__ vt)
{
    const int n0  = blockIdx.x * 32;
    const int b   = blockIdx.y;
    const int tid = threadIdx.x;
    const int w = tid >> 6, lane = tid & 63, quad = lane >> 4, nn = lane & 15;

    __shared__ __align__(16) short xsT[32 * 136];
    __shared__ __align__(16) short vstage[4096];   // 2 kg x 4 ct x 512

    #pragma unroll
    for (int p = 0; p < 4; ++p) {
        int idx = tid + p * 256;
        int cc = idx >> 3, n4 = (idx & 7) * 4;
        f32x4 xv = *(const f32x4*)&x[((size_t)(b * NC + cc)) * NNPOS + n0 + n4];
        #pragma unroll
        for (int j = 0; j < 4; ++j)
            xsT[(n4 + j) * 136 + cc] = bf16s(xv[j]);
    }

    s16x8 af[3][4];
    bool  live[3];
    f32x4 biasv[3];
    #pragma unroll
    for (int t = 0; t < 3; ++t) {
        int rid = 3 * w + t;
        int R   = rid * 16;
        const float* wsrc = nullptr; const float* bsrc = nullptr; int row0 = 0;
        float scale = 1.0f;
        if (rid < 8)        { wsrc = wv; bsrc = bv; row0 = R; }
        else if (rid == 8)  { wsrc = wq; bsrc = bq; row0 = 0; scale = LOG2E; }
        else if (rid == 10) { wsrc = wk; bsrc = bk; row0 = 0; }
        live[t] = (wsrc != nullptr);
        #pragma unroll
        for (int r = 0; r < 4; ++r)
            biasv[t][r] = live[t] ? scale * bsrc[row0 + quad * 4 + r] : 0.0f;
        if (live[t]) {
            #pragma unroll
            for (int ks = 0; ks < 4; ++ks) {
                const float* src = wsrc + (size_t)(row0 + nn) * NC + ks * 32 + quad * 8;
                f32x4 wa = *(const f32x4*)src;
                f32x4 wb = *(const f32x4*)(src + 4);
                s16x8 f;
                #pragma unroll
                for (int j = 0; j < 4; ++j) {
                    f[j]     = bf16s(scale * wa[j]);
                    f[j + 4] = bf16s(scale * wb[j]);
                }
                af[t][ks] = f;
            }
        }
    }
    __syncthreads();

    f32x4 acc[3][2];
    #pragma unroll
    for (int t = 0; t < 3; ++t)
        #pragma unroll
        for (int nt = 0; nt < 2; ++nt)
            acc[t][nt] = biasv[t];

    #pragma unroll
    for (int nt = 0; nt < 2; ++nt) {
        s16x8 bf[4];
        #pragma unroll
        for (int ks = 0; ks < 4; ++ks)
            bf[ks] = *(const s16x8*)&xsT[(nt * 16 + nn) * 136 + ks * 32 + quad * 8];
        #pragma unroll
        for (int t = 0; t < 3; ++t)
            if (live[t])
                #pragma unroll
                for (int ks = 0; ks < 4; ++ks)
                    acc[t][nt] = __builtin_amdgcn_mfma_f32_16x16x32_bf16(af[t][ks], bf[ks], acc[t][nt], 0, 0, 0);
    }

    // V-slot key permutation: swap bits 2<->3 of (key%16)
    const int slot = (nn & 3) | ((nn & 4) << 1) | ((nn & 8) >> 1);

    #pragma unroll
    for (int t = 0; t < 3; ++t) {
        if (!live[t]) continue;
        const int rid = 3 * w + t;
        #pragma unroll
        for (int nt = 0; nt < 2; ++nt) {
            if (rid < 8) {
                #pragma unroll
                for (int r = 0; r < 4; ++r) {
                    int row = rid * 16 + quad * 4 + r;
                    vstage[(((nt << 2) | (row >> 5)) << 9) +
                           ((slot >> 3) << 8) + ((row & 31) << 3) + (slot & 7)]
                        = bf16s(acc[t][nt][r]);
                }
            } else {
                short4 pk;
                pk.x = bf16s(acc[t][nt][0]);
                pk.y = bf16s(acc[t][nt][1]);
                pk.z = bf16s(acc[t][nt][2]);
                pk.w = bf16s(acc[t][nt][3]);
                int n = n0 + nt * 16 + nn;
                short* dst = (rid == 8 ? qb : kb) +
                             ((size_t)(b * NNPOS) + n) * 16 + quad * 4;
                *reinterpret_cast<short4*>(dst) = pk;
            }
        }
    }
    __syncthreads();

    // coalesced copy-out: 8 KB tile, 256 threads x 2 x 16B
    {
        short* vdst = vt + ((size_t)(b * 256) + (n0 >> 4)) * 2048;
        #pragma unroll
        for (int p = 0; p < 2; ++p) {
            int off = (tid + p * 256) * 8;
            *(s16x8*)&vdst[off] = *(const s16x8*)&vstage[off];
        }
    }
}

// ------------------------------------------------------------------
// Kernel 2 (R15): single-pass attention, IN-BLOCK key split.
// Block = one 32-query tile x ALL 4096 keys; wave w handles keys
// [w*1024, w*1024+1024) with the barrier-free private-V inner loop
// (V loads 16B/lane dense, R11 layout; K 1-iter reg prefetch).
// Partials stay fp32 in regs; combined at block end via a 2-round
// LDS tree (w0/w1 write A/B, w2/w3 add in); epilogue applies
// 1/sum(l), gamma, +x and writes out DIRECTLY.
// Eliminated vs R14: Ow (67MB R/W), lw, combine kernel, all main-loop
// barriers + global_load_lds drains.
// Grid 512 flat = 2 blocks/CU, 2 waves/SIMD. Flat-idx swizzle pins
// XCD k to batch b=k/2 (per-XCD hot set ~1.2MB << 4MiB L2; no write
// stream thrashing it). Perf-only assumption (idx%8 = XCD); partition
// is valid regardless.
// ------------------------------------------------------------------
__global__ __launch_bounds__(256, 2) void attn_kernel(
    const short* __restrict__ qb, const short* __restrict__ kb,
    const short* __restrict__ vt,
    const float* __restrict__ xg, const float* __restrict__ gamma,
    float* __restrict__ out)
{
    const int idx = blockIdx.x;
    const int b   = (idx & 7) >> 1;                    // XCD-pinned batch
    const int qy  = ((idx >> 3) << 1) | (idx & 1);     // 0..127
    const int q0  = qy * 32;
    const int tid = threadIdx.x;
    const int w = tid >> 6, lane = tid & 63, h = lane >> 5, c31 = lane & 31;

    // combine tree buffers: 2 x [128 c][33 q-padded] + lp + inv  (~34.4 KB)
    __shared__ float cbufA[128][33];
    __shared__ float cbufB[128][33];
    __shared__ float lpbuf[4][32];
    __shared__ float invbuf[32];

    s16x8 bq = *(const s16x8*)(qb + ((size_t)(b * NNPOS) + q0 + c31) * 16 + h * 8);

    f32x16 acc[4];
    #pragma unroll
    for (int ct = 0; ct < 4; ++ct)
        #pragma unroll
        for (int r = 0; r < 16; ++r) acc[ct][r] = 0.0f;
    float lp0 = 0.f, lp1 = 0.f;

    const short* kbp = kb + (size_t)(b * NNPOS) * 16;
    const short* vbp = vt + (size_t)b * (NC * NNPOS);

    f32x16 z;
    #pragma unroll
    for (int r = 0; r < 16; ++r) z[r] = 0.0f;

    // wave's private 1024-key slice
    int m0 = w * 1024;
    s16x8 ak0 = *(const s16x8*)(kbp + (size_t)(m0      + c31) * 16 + h * 8);
    s16x8 ak1 = *(const s16x8*)(kbp + (size_t)(m0 + 32 + c31) * 16 + h * 8);

    #pragma unroll 1
    for (int it = 0; it < 16; ++it) {
        const int kg0 = (w * 1024 >> 4) + it * 4;

        // V groups 0,1 (dense lane-linear: 1KB contiguous per wave-instr)
        s16x8 vb01[2][4];
        #pragma unroll
        for (int p = 0; p < 2; ++p)
            #pragma unroll
            for (int ct = 0; ct < 4; ++ct)
                vb01[p][ct] = *(const s16x8*)(vbp +
                    (((size_t)(kg0 + p) * 4 + ct) << 9) + (lane << 3));

        // scores -> exp/pack (sequential: 16-score liveness)
        s16x8 pa[4];
        {
            f32x16 sc = __builtin_amdgcn_mfma_f32_32x32x16_bf16(ak0, bq, z, 0, 0, 0);
            exppack(sc, pa[0], pa[1], lp0, lp1);
            sc = __builtin_amdgcn_mfma_f32_32x32x16_bf16(ak1, bq, z, 0, 0, 0);
            exppack(sc, pa[2], pa[3], lp0, lp1);
        }

        // prefetch next iter's K (ak0/ak1 dead after the score MFMAs)
        if (it + 1 < 16) {
            m0 += 64;
            ak0 = *(const s16x8*)(kbp + (size_t)(m0      + c31) * 16 + h * 8);
            ak1 = *(const s16x8*)(kbp + (size_t)(m0 + 32 + c31) * 16 + h * 8);
        }

        // PV groups 0,1
        #pragma unroll
        for (int p = 0; p < 2; ++p)
            #pragma unroll
            for (int ct = 0; ct < 4; ++ct)
                acc[ct] = __builtin_amdgcn_mfma_f32_32x32x16_bf16(
                    pa[p], vb01[p][ct], acc[ct], 0, 0, 0);

        // V groups 2,3 (after vb01 dead: no register-peak growth)
        s16x8 vb23[2][4];
        #pragma unroll
        for (int p = 0; p < 2; ++p)
            #pragma unroll
            for (int ct = 0; ct < 4; ++ct)
                vb23[p][ct] = *(const s16x8*)(vbp +
                    (((size_t)(kg0 + 2 + p) * 4 + ct) << 9) + (lane << 3));
        #pragma unroll
        for (int p = 0; p < 2; ++p)
            #pragma unroll
            for (int ct = 0; ct < 4; ++ct)
                acc[ct] = __builtin_amdgcn_mfma_f32_32x32x16_bf16(
                    pa[2 + p], vb23[p][ct], acc[ct], 0, 0, 0);
    }

    // per-wave l sum for each of the 32 queries
    float lp = lp0 + lp1;
    lp += __shfl_xor(lp, 32, 64);
    if (lane < 32) lpbuf[w][c31] = lp;

    // ---- in-block combine, round 1: w0 -> A, w1 -> B ----
    if (w < 2) {
        float (*cb)[33] = (w == 0) ? cbufA : cbufB;
        #pragma unroll
        for (int ct = 0; ct < 4; ++ct)
            #pragma unroll
            for (int r = 0; r < 16; ++r) {
                int q = (r & 3) + 8 * (r >> 2) + 4 * h;
                cb[ct * 32 + c31][q] = acc[ct][r];
            }
    }
    __syncthreads();

    // ---- round 2: w2 += A, w3 += B; w0 lanes compute 1/sum(l) ----
    if (w >= 2) {
        float (*cb)[33] = (w == 2) ? cbufA : cbufB;
        #pragma unroll
        for (int ct = 0; ct < 4; ++ct)
            #pragma unroll
            for (int r = 0; r < 16; ++r) {
                int q = (r & 3) + 8 * (r >> 2) + 4 * h;
                cb[ct * 32 + c31][q] += acc[ct][r];
            }
    }
    if (tid < 32)
        invbuf[tid] = 1.0f / (lpbuf[0][tid] + lpbuf[1][tid] +
                              lpbuf[2][tid] + lpbuf[3][tid]);
    __syncthreads();

    // ---- epilogue: out[b][c][q0+q] = g*(A+B)*inv + x ----
    {
        const float g = gamma[0];
        const int c  = tid >> 1;
        const int nh = (tid & 1) * 16;
        size_t base = ((size_t)(b * NC + c)) * NNPOS + q0 + nh;
        #pragma unroll
        for (int j = 0; j < 16; j += 4) {
            f32x4 xv = *(const f32x4*)&xg[base + j];
            f32x4 o;
            #pragma unroll
            for (int e = 0; e < 4; ++e) {
                int q = nh + j + e;
                o[e] = g * (cbufA[c][q] + cbufB[c][q]) * invbuf[q] + xv[e];
            }
            *(f32x4*)&out[base + j] = o;
        }
    }
}

// ------------------------------------------------------------------
extern "C" void kernel_launch(void* const* d_in, const int* in_sizes, int n_in,
                              void* d_out, int out_size, void* d_ws, size_t ws_size,
                              hipStream_t stream) {
    const float* x     = (const float*)d_in[0];
    const float* wq    = (const float*)d_in[1];
    const float* bq    = (const float*)d_in[2];
    const float* wk    = (const float*)d_in[3];
    const float* bk    = (const float*)d_in[4];
    const float* wv    = (const float*)d_in[5];
    const float* bv    = (const float*)d_in[6];
    const float* gamma = (const float*)d_in[7];
    float* out = (float*)d_out;

    // ws: qb 512KB | kb 512KB | vt 4MB  (no Ow/lw anymore)
    short* qb = (short*)d_ws;
    short* kb = qb + (size_t)NB * NNPOS * 16;
    short* vt = kb + (size_t)NB * NNPOS * 16;

    qkv_kernel<<<dim3(128, NB), 256, 0, stream>>>(x, wq, bq, wk, bk, wv, bv, qb, kb, vt);
    attn_kernel<<<dim3(512), 256, 0, stream>>>(qb, kb, vt, x, gamma, out);
}